// Round 1
// baseline (83.397 us; speedup 1.0000x reference)
//
#include <hip/hip_runtime.h>

#define N 1024
#define D 128
#define PAD 132            // 128+4: rows 16B-aligned, bank stride 4 -> 2-way (free)
#define MAGIC 0x3C96A5E1u  // "rowsum initialized" flag value (ws is poisoned)

// ---------------------------------------------------------------------------
// Fully fused: scores + relu + exp + row-sum (device atomics) + in-kernel grid
// barrier + normalize. S is written exactly once; exp values stay in VGPRs
// across the barrier. No separate softmax pass.
//
// Softmax without max-subtraction: scores = relu(.) >= 0 and bounded (~<=15
// realistically, sum|w|*max|diff| ~ 89 absolute worst), exp() cannot overflow
// fp32 in practice; the max term cancels in the ratio anyway.
//
// Grid = (16,16) = 256 blocks, 256 threads, 64x64 tile, micro-tile 4x4:
// VALU:ds_read_b128 = 128:8 = 16:1 (was 10.7:1), staging traffic halved.
// Co-residency for the barrier: LDS 67.6 KB (<80 KB) and VGPR<256 allow 2
// blocks/CU in the worst packing, so all 256 blocks are resident. Spins are
// iteration-capped: a protocol failure becomes a wrong answer, not a hang.
// ---------------------------------------------------------------------------
__global__ __launch_bounds__(256) void fused_kernel(
    const float* __restrict__ x, const float* __restrict__ w,
    const float* __restrict__ bias, float* __restrict__ S,
    unsigned int* __restrict__ ws) {
  __shared__ float sxi[64 * PAD];
  __shared__ float sxj[64 * PAD];

  unsigned int* flag    = ws;        // ws + 0
  unsigned int* counter = ws + 32;   // ws + 128 B (own cache line)
  float* rowsum = reinterpret_cast<float*>(ws) + 1024;  // ws + 4 KiB

  const int t  = threadIdx.x;
  const int bi = blockIdx.y * 64;
  const int bj = blockIdx.x * 64;

  // ---- block (0,0): zero rowsum + counter, then release the flag ----------
  if (blockIdx.x == 0 && blockIdx.y == 0) {
    #pragma unroll
    for (int k = 0; k < 4; ++k)
      __hip_atomic_store(&rowsum[t * 4 + k], 0.0f, __ATOMIC_RELAXED,
                         __HIP_MEMORY_SCOPE_AGENT);
    if (t == 0)
      __hip_atomic_store(counter, 0u, __ATOMIC_RELAXED,
                         __HIP_MEMORY_SCOPE_AGENT);
    __syncthreads();
    __threadfence();   // agent-scope: zeroes visible before flag
    if (t == 0)
      __hip_atomic_store(flag, MAGIC, __ATOMIC_RELEASE,
                         __HIP_MEMORY_SCOPE_AGENT);
  }

  // ---- stage both 64-row tiles: coalesced float4, one barrier --------------
  {
    const int c  = t & 31;   // float4 column 0..31
    const int r0 = t >> 5;   // 0..7
    #pragma unroll
    for (int p = 0; p < 8; ++p) {
      const int r = r0 + p * 8;
      const float4 vi = reinterpret_cast<const float4*>(x)[(bi + r) * 32 + c];
      *reinterpret_cast<float4*>(&sxi[r * PAD + c * 4]) = vi;
      const float4 vj = reinterpret_cast<const float4*>(x)[(bj + r) * 32 + c];
      *reinterpret_cast<float4*>(&sxj[r * PAD + c * 4]) = vj;
    }
  }
  __syncthreads();

  const int tx = t & 15;   // cols tx + 16*b, b=0..3
  const int ty = t >> 4;   // rows ty + 16*a, a=0..3

  float acc[4][4];
  #pragma unroll
  for (int a = 0; a < 4; ++a)
    #pragma unroll
    for (int b = 0; b < 4; ++b) acc[a][b] = 0.f;

  #pragma unroll 2
  for (int d = 0; d < D; d += 4) {
    const float4 W = reinterpret_cast<const float4*>(w)[d >> 2];  // s_load
    float4 A[4], B[4];
    #pragma unroll
    for (int a = 0; a < 4; ++a)   // 4 addrs/wave, 16-lane broadcast
      A[a] = *reinterpret_cast<const float4*>(&sxi[(ty + 16 * a) * PAD + d]);
    #pragma unroll
    for (int b = 0; b < 4; ++b)   // 16 addrs/wave, 2-way alias (free)
      B[b] = *reinterpret_cast<const float4*>(&sxj[(tx + 16 * b) * PAD + d]);

    #pragma unroll
    for (int a = 0; a < 4; ++a) {
      #pragma unroll
      for (int b = 0; b < 4; ++b) {
        float s = acc[a][b];
        s = fmaf(fabsf(A[a].x - B[b].x), W.x, s);
        s = fmaf(fabsf(A[a].y - B[b].y), W.y, s);
        s = fmaf(fabsf(A[a].z - B[b].z), W.z, s);
        s = fmaf(fabsf(A[a].w - B[b].w), W.w, s);
        acc[a][b] = s;
      }
    }
  }

  // ---- epilogue: relu + exp (no max-sub), per-row partial sums -------------
  const float bv = bias[0];
  float e[4][4];
  float part[4];
  #pragma unroll
  for (int a = 0; a < 4; ++a) {
    float p = 0.f;
    #pragma unroll
    for (int b = 0; b < 4; ++b) {
      const float s  = fmaxf(acc[a][b] + bv, 0.f);
      const float ev = __expf(s);
      e[a][b] = ev;
      p += ev;
    }
    // reduce across the 16-lane col group (xor<16 stays within group)
    #pragma unroll
    for (int o = 1; o < 16; o <<= 1) p += __shfl_xor(p, o, 64);
    part[a] = p;
  }

  // ---- wait for init flag, then accumulate row sums ------------------------
  if (t == 0) {
    for (unsigned it = 0; it < (1u << 26); ++it) {
      if (__hip_atomic_load(flag, __ATOMIC_ACQUIRE,
                            __HIP_MEMORY_SCOPE_AGENT) == MAGIC) break;
      __builtin_amdgcn_s_sleep(2);
    }
  }
  __syncthreads();

  if (tx == 0) {
    #pragma unroll
    for (int a = 0; a < 4; ++a)
      atomicAdd(&rowsum[bi + ty + 16 * a], part[a]);
  }
  __syncthreads();   // barrier drains vmcnt: all this block's adds are done

  // ---- grid barrier: arrive + spin -----------------------------------------
  if (t == 0) {
    __hip_atomic_fetch_add(counter, 1u, __ATOMIC_ACQ_REL,
                           __HIP_MEMORY_SCOPE_AGENT);
    for (unsigned it = 0; it < (1u << 26); ++it) {
      if (__hip_atomic_load(counter, __ATOMIC_ACQUIRE,
                            __HIP_MEMORY_SCOPE_AGENT) >= 256u) break;
      __builtin_amdgcn_s_sleep(2);
    }
  }
  __syncthreads();

  // ---- normalize from registers, single write of S -------------------------
  float rs[4];
  #pragma unroll
  for (int a = 0; a < 4; ++a)
    rs[a] = 1.0f / __hip_atomic_load(&rowsum[bi + ty + 16 * a],
                                     __ATOMIC_RELAXED, __HIP_MEMORY_SCOPE_AGENT);

  #pragma unroll
  for (int a = 0; a < 4; ++a) {
    const int row = bi + ty + 16 * a;
    #pragma unroll
    for (int b = 0; b < 4; ++b)
      S[row * N + bj + tx + 16 * b] = e[a][b] * rs[a];
  }
}

extern "C" void kernel_launch(void* const* d_in, const int* in_sizes, int n_in,
                              void* d_out, int out_size, void* d_ws, size_t ws_size,
                              hipStream_t stream) {
  const float* x = (const float*)d_in[0];
  const float* w = (const float*)d_in[1];
  const float* b = (const float*)d_in[2];
  float* out = (float*)d_out;
  unsigned int* ws = (unsigned int*)d_ws;

  dim3 grid(N / 64, N / 64);   // (16,16) = 256 blocks, all co-resident
  fused_kernel<<<grid, 256, 0, stream>>>(x, w, b, out, ws);
}